// Round 1
// baseline (552.278 us; speedup 1.0000x reference)
//
#include <hip/hip_runtime.h>

#define T_STEPS  2048
#define BH       128
#define KFAST    32
#define VFAST    64
#define KSLOW    128
#define VSLOW    64
#define VB       32            // v-columns per block (v-split = 2)
#define NT       4             // timesteps per barrier iteration
#define NITER    (T_STEPS / NT)
#define NTHREADS 512
#define PER_STEP 389           // staged floats per step (384 arrays + 5 scalars)
#define STG_STRIDE 392         // Stage struct size in floats
#define NROLES   4             // ceil(NT*PER_STEP / NTHREADS)

struct __align__(16) Stage {
    float ks[KSLOW];   // offset 0
    float qs[KSLOW];   // 128
    float vs[VB];      // 256
    float kf[KFAST];   // 288
    float qf[KFAST];   // 320
    float vf[VB];      // 352
    float sc[8];       // 384: df, dsl, g, mf, ms, pad
};                     // 392 floats = 1568 B, 16B aligned

static_assert(sizeof(Stage) == STG_STRIDE * 4, "stage layout");

__global__ __launch_bounds__(NTHREADS, 2)
void e90_kernel(const float* __restrict__ k_fast,  const float* __restrict__ v_fast,
                const float* __restrict__ q_fast,  const float* __restrict__ decay_fast,
                const float* __restrict__ k_slow,  const float* __restrict__ v_slow,
                const float* __restrict__ q_slow,  const float* __restrict__ decay_slow,
                const float* __restrict__ slow_gate, const float* __restrict__ mix_fast,
                const float* __restrict__ mix_slow, const float* __restrict__ S_fast0,
                const float* __restrict__ S_slow0, float* __restrict__ dout)
{
    __shared__ Stage stg[2][NT];
    __shared__ float red[2][NT][8][32];

    const int tid  = threadIdx.x;
    const int bid  = blockIdx.x;
    // XCD-pairing swizzle: the two v-halves of a pair land on the same XCD (L2 share)
    const int xcd  = bid & 7;
    const int jj   = bid >> 3;          // 0..31
    const int p    = xcd * 16 + (jj >> 1);   // (b*H + h) in 0..127
    const int v0   = (jj & 1) * VB;
    const int v    = tid & 31;
    const int grp  = tid >> 5;          // 0..15 k-group
    const int wid  = tid >> 6;          // 0..7 wave id
    const int lane = tid & 63;

    // ---- staging role setup (once) ----
    const float* rptr[NROLES];
    int rstride[NROLES], rlds[NROLES], rstep[NROLES];
#pragma unroll
    for (int r = 0; r < NROLES; ++r) {
        int e = tid + NTHREADS * r;
        if (e >= NT * PER_STEP) {                 // dummy role (harmless)
            rptr[r] = k_slow; rstride[r] = 0; rlds[r] = 389; rstep[r] = 0;
        } else {
            int s = e / PER_STEP;
            int o = e - s * PER_STEP;
            const float* base; int stride, off;
            if (o < 128)      { base = k_slow; stride = BH*KSLOW; off = p*KSLOW + o; }
            else if (o < 256) { base = q_slow; stride = BH*KSLOW; off = p*KSLOW + (o-128); }
            else if (o < 288) { base = v_slow; stride = BH*VSLOW; off = p*VSLOW + v0 + (o-256); }
            else if (o < 320) { base = k_fast; stride = BH*KFAST; off = p*KFAST + (o-288); }
            else if (o < 352) { base = q_fast; stride = BH*KFAST; off = p*KFAST + (o-320); }
            else if (o < 384) { base = v_fast; stride = BH*VFAST; off = p*VFAST + v0 + (o-352); }
            else {
                base = (o == 384) ? decay_fast : (o == 385) ? decay_slow :
                       (o == 386) ? slow_gate  : (o == 387) ? mix_fast   : mix_slow;
                stride = BH; off = p;
            }
            rptr[r] = base + off; rstride[r] = stride;
            rlds[r] = s * STG_STRIDE + o; rstep[r] = s;
        }
    }

    // ---- state init ----
    float Ss[8], Sf[2];
#pragma unroll
    for (int j = 0; j < 8; ++j)
        Ss[j] = S_slow0[(p*KSLOW + grp*8 + j)*VSLOW + v0 + v];
#pragma unroll
    for (int j = 0; j < 2; ++j)
        Sf[j] = S_fast0[(p*KFAST + grp*2 + j)*VFAST + v0 + v];

    float* lds_f = (float*)&stg[0][0];
    float* out_y = dout + BH*KFAST*VFAST + BH*KSLOW*VSLOW;   // output section

    float preA[NROLES], preB[NROLES];

#define PREFETCH(DST, TBASE) do {                                             \
    _Pragma("unroll")                                                         \
    for (int r = 0; r < NROLES; ++r) {                                        \
        int t_ = (TBASE) + rstep[r];                                          \
        if (t_ > T_STEPS - 1) t_ = T_STEPS - 1;                               \
        DST[r] = rptr[r][t_ * rstride[r]];                                    \
    } } while (0)

#define STAGE(PB, SRC) do {                                                   \
    float* lb_ = lds_f + (PB) * (NT * STG_STRIDE);                            \
    _Pragma("unroll")                                                         \
    for (int r = 0; r < NROLES; ++r) lb_[rlds[r]] = SRC[r];                   \
    } while (0)

#define COMPUTE(I) do {                                                       \
    const int pb_ = (I) & 1;                                                  \
    _Pragma("unroll")                                                         \
    for (int s = 0; s < NT; ++s) {                                            \
        const Stage* st = &stg[pb_][s];                                       \
        const float4 sc0 = *reinterpret_cast<const float4*>(&st->sc[0]);      \
        const float msx = st->sc[4];                                          \
        const float df_ = sc0.x;                                              \
        const float a_  = __builtin_fmaf(sc0.z, sc0.y, 1.0f - sc0.z);         \
        const float vvs = sc0.z * st->vs[v];                                  \
        const float vvf = st->vf[v];                                          \
        const float4 k0 = *reinterpret_cast<const float4*>(&st->ks[grp*8]);   \
        const float4 k1 = *reinterpret_cast<const float4*>(&st->ks[grp*8+4]); \
        const float4 q0 = *reinterpret_cast<const float4*>(&st->qs[grp*8]);   \
        const float4 q1 = *reinterpret_cast<const float4*>(&st->qs[grp*8+4]); \
        const float2 kf2 = *reinterpret_cast<const float2*>(&st->kf[grp*2]);  \
        const float2 qf2 = *reinterpret_cast<const float2*>(&st->qf[grp*2]);  \
        const float kk[8] = {k0.x,k0.y,k0.z,k0.w,k1.x,k1.y,k1.z,k1.w};        \
        const float qq[8] = {q0.x,q0.y,q0.z,q0.w,q1.x,q1.y,q1.z,q1.w};        \
        float ps0 = 0.f, ps1 = 0.f;                                           \
        _Pragma("unroll")                                                     \
        for (int j = 0; j < 8; j += 2) {                                      \
            Ss[j]   = __builtin_fmaf(a_, Ss[j],   kk[j]   * vvs);             \
            ps0     = __builtin_fmaf(qq[j],   Ss[j],   ps0);                  \
            Ss[j+1] = __builtin_fmaf(a_, Ss[j+1], kk[j+1] * vvs);             \
            ps1     = __builtin_fmaf(qq[j+1], Ss[j+1], ps1);                  \
        }                                                                     \
        float pf_ = 0.f;                                                      \
        Sf[0] = __builtin_fmaf(df_, Sf[0], kf2.x * vvf);                      \
        pf_   = __builtin_fmaf(qf2.x, Sf[0], pf_);                            \
        Sf[1] = __builtin_fmaf(df_, Sf[1], kf2.y * vvf);                      \
        pf_   = __builtin_fmaf(qf2.y, Sf[1], pf_);                            \
        float part = __builtin_fmaf(sc0.w, pf_, msx * (ps0 + ps1));           \
        part += __shfl_xor(part, 32);                                         \
        if (lane < 32) red[pb_][s][wid][v] = part;                            \
    } } while (0)

#define REDUCE(IPREV) do {                                                    \
    const int pp_ = (IPREV) & 1;                                              \
    if (tid < 64 * NT) {                                                      \
        const int s_ = tid >> 6, u_ = tid & 63, vv_ = u_ & 31, hi_ = u_ >> 5; \
        float acc = red[pp_][s_][hi_*4+0][vv_];                               \
        acc += red[pp_][s_][hi_*4+1][vv_];                                    \
        acc += red[pp_][s_][hi_*4+2][vv_];                                    \
        acc += red[pp_][s_][hi_*4+3][vv_];                                    \
        acc += __shfl_xor(acc, 32);                                           \
        if (hi_ == 0)                                                         \
            out_y[(((IPREV)*NT + s_)*BH + p)*VFAST + v0 + vv_] = acc;         \
    } } while (0)

    // ---- prologue: fill buf0 (iter 0) and preB (iter 1) ----
    PREFETCH(preA, 0);
    STAGE(0, preA);
    PREFETCH(preB, NT);

    // ---- main loop: 2 iterations (8 timesteps) per pass, 1 barrier / 4 steps ----
    for (int i = 0; i < NITER; i += 2) {
        __syncthreads();
        PREFETCH(preA, (i + 2) * NT);   // depth-2 prefetch for iter i+2
        if (i > 0) REDUCE(i - 1);
        COMPUTE(i);                     // reads stg[0], writes red[0]
        STAGE(1, preB);                 // stage iter i+1 into stg[1]

        __syncthreads();
        PREFETCH(preB, (i + 3) * NT);   // for iter i+3
        REDUCE(i);
        COMPUTE(i + 1);                 // reads stg[1], writes red[1]
        STAGE(0, preA);                 // stage iter i+2 into stg[0]
    }

    __syncthreads();
    REDUCE(NITER - 1);

    // ---- final states ----
    float* outSf = dout;
    float* outSs = dout + BH*KFAST*VFAST;
#pragma unroll
    for (int j = 0; j < 8; ++j)
        outSs[(p*KSLOW + grp*8 + j)*VSLOW + v0 + v] = Ss[j];
#pragma unroll
    for (int j = 0; j < 2; ++j)
        outSf[(p*KFAST + grp*2 + j)*VFAST + v0 + v] = Sf[j];

#undef PREFETCH
#undef STAGE
#undef COMPUTE
#undef REDUCE
}

extern "C" void kernel_launch(void* const* d_in, const int* in_sizes, int n_in,
                              void* d_out, int out_size, void* d_ws, size_t ws_size,
                              hipStream_t stream)
{
    const float* k_fast     = (const float*)d_in[0];
    const float* v_fast     = (const float*)d_in[1];
    const float* q_fast     = (const float*)d_in[2];
    const float* decay_fast = (const float*)d_in[3];
    const float* k_slow     = (const float*)d_in[4];
    const float* v_slow     = (const float*)d_in[5];
    const float* q_slow     = (const float*)d_in[6];
    const float* decay_slow = (const float*)d_in[7];
    const float* slow_gate  = (const float*)d_in[8];
    const float* mix_fast   = (const float*)d_in[9];
    const float* mix_slow   = (const float*)d_in[10];
    const float* S_fast0    = (const float*)d_in[11];
    const float* S_slow0    = (const float*)d_in[12];
    float* dout = (float*)d_out;

    e90_kernel<<<dim3(256), dim3(NTHREADS), 0, stream>>>(
        k_fast, v_fast, q_fast, decay_fast,
        k_slow, v_slow, q_slow, decay_slow,
        slow_gate, mix_fast, mix_slow, S_fast0, S_slow0, dout);
}

// Round 2
// 215.389 us; speedup vs baseline: 2.5641x; 2.5641x over previous
//
#include <hip/hip_runtime.h>

#define T_STEPS 2048
#define BH      128
#define KS_     128
#define VS_     64
#define KF_     32
#define VF_     64
#define LCH     32
#define NC      (T_STEPS / LCH)
#define NTHR    512

typedef __attribute__((ext_vector_type(8))) short short8;
typedef __attribute__((ext_vector_type(16))) float f32x16;

#define MFMA32(a,b,c) __builtin_amdgcn_mfma_f32_32x32x16_bf16((a),(b),(c),0,0,0)
#define CROW(r,hi) (((r)&3) + 8*((r)>>2) + 4*(hi))

__device__ __forceinline__ unsigned short f2b(float x) {
    union { float f; unsigned u; } v; v.f = x;
    unsigned r = v.u + 0x7FFFu + ((v.u >> 16) & 1u);
    return (unsigned short)(r >> 16);
}

__device__ __forceinline__ short8 ld8(const unsigned short* p) {
    return *(const short8*)p;
}

__global__ __launch_bounds__(NTHR, 2)
void e90_mfma(const float* __restrict__ k_fast,  const float* __restrict__ v_fast,
              const float* __restrict__ q_fast,  const float* __restrict__ decay_fast,
              const float* __restrict__ k_slow,  const float* __restrict__ v_slow,
              const float* __restrict__ q_slow,  const float* __restrict__ decay_slow,
              const float* __restrict__ slow_gate, const float* __restrict__ mix_fast,
              const float* __restrict__ mix_slow, const float* __restrict__ S_fast0,
              const float* __restrict__ S_slow0, float* __restrict__ dout)
{
    // bf16 LDS tensors; B-operands stored transposed [col][k]; rows padded
    // to 136/40 ushorts (272B/80B) so 32-row b128 reads are ~4-way max.
    __shared__ __align__(16) unsigned short Qs [LCH][136]; // ms*b_t*q_slow  [t][k]
    __shared__ __align__(16) unsigned short Ksl[LCH][136]; // k_slow/b_s     [s][k]
    __shared__ __align__(16) unsigned short KTs[KS_][40];  // transpose      [k][s]
    __shared__ __align__(16) unsigned short Sbs[LCH][136]; // old S_slow^T   [v][k]
    __shared__ __align__(16) unsigned short Psl[LCH][40];  // masked P_slow  [t][s]
    __shared__ __align__(16) unsigned short VTs[LCH][40];  // (g*v_slow)^T   [v][s]
    __shared__ __align__(16) unsigned short WTs[LCH][40];  // (bL*g*v)^T     [v][s]
    __shared__ __align__(16) unsigned short Qfl[LCH][40];
    __shared__ __align__(16) unsigned short Kfl[LCH][40];
    __shared__ __align__(16) unsigned short KTf[KF_][40];
    __shared__ __align__(16) unsigned short Sbfl[LCH][40]; // old S_fast^T [v][k]
    __shared__ __align__(16) unsigned short Pfl[LCH][40];
    __shared__ __align__(16) unsigned short VTf[LCH][40];
    __shared__ __align__(16) unsigned short WTf[LCH][40];
    __shared__ float scl[7][LCH];  // 0:bs 1:1/bs 2:ms*bs 3:g 4:bf 5:1/bf 6:mf*bf

    const int tid  = threadIdx.x;
    const int bid  = blockIdx.x;
    const int xcd  = bid & 7;
    const int jj   = bid >> 3;
    const int p    = xcd * 16 + (jj >> 1);   // (b*H+h) 0..127
    const int v0   = (jj & 1) * 32;          // v-half
    const int lane = tid & 63;
    const int wid  = tid >> 6;
    const int l31  = lane & 31;
    const int hi   = lane >> 5;

    float* out_y = dout + BH*KF_*VF_ + BH*KS_*VS_;

    // ---- persistent state in C-fragment layout (w0-3: slow tiles, w4: fast) ----
    f32x16 Sst;
#pragma unroll
    for (int r = 0; r < 16; ++r) Sst[r] = 0.0f;
    if (wid < 4) {
#pragma unroll
        for (int r = 0; r < 16; ++r) {
            int kr = 32*wid + CROW(r,hi);
            Sst[r] = S_slow0[((size_t)p*KS_ + kr)*VS_ + v0 + l31];
        }
#pragma unroll
        for (int r = 0; r < 16; ++r) Sbs[l31][32*wid + CROW(r,hi)] = f2b(Sst[r]);
    } else if (wid == 4) {
#pragma unroll
        for (int r = 0; r < 16; ++r) {
            int kr = CROW(r,hi);
            Sst[r] = S_fast0[((size_t)p*KF_ + kr)*VF_ + v0 + l31];
        }
#pragma unroll
        for (int r = 0; r < 16; ++r) Sbfl[l31][CROW(r,hi)] = f2b(Sst[r]);
    }

    // ---- chunk-input prefetch registers ----
    float4 pKs0, pKs1, pQs0, pQs1;
    float2 pVs, pVf, pKf, pQf;
    float pS0 = 0.f, pS1 = 0.f, pS2 = 0.f;

    const int s_  = tid >> 4;          // 0..31 (row for all per-chunk arrays)
    const int k0_ = (tid & 15) * 8;    // slow-k offset
    const int j0_ = (tid & 15) * 2;    // 32-wide offset

#define LOADCHUNK(CIDX) do {                                                   \
    int tc_ = (CIDX); if (tc_ > NC-1) tc_ = NC-1;                              \
    const int tb_ = tc_ * LCH;                                                 \
    const float* bk_ = k_slow + ((size_t)(tb_+s_)*BH + p)*KS_ + k0_;           \
    pKs0 = *(const float4*)bk_;  pKs1 = *(const float4*)(bk_+4);               \
    const float* bq_ = q_slow + ((size_t)(tb_+s_)*BH + p)*KS_ + k0_;           \
    pQs0 = *(const float4*)bq_;  pQs1 = *(const float4*)(bq_+4);               \
    pVs = *(const float2*)(v_slow + ((size_t)(tb_+s_)*BH + p)*VS_ + v0 + j0_); \
    pVf = *(const float2*)(v_fast + ((size_t)(tb_+s_)*BH + p)*VF_ + v0 + j0_); \
    pKf = *(const float2*)(k_fast + ((size_t)(tb_+s_)*BH + p)*KF_ + j0_);      \
    pQf = *(const float2*)(q_fast + ((size_t)(tb_+s_)*BH + p)*KF_ + j0_);      \
    if (wid == 0) {                                                            \
        int tl_ = tb_ + l31;                                                   \
        const float* a0_ = (lane < 32) ? decay_slow : decay_fast;              \
        const float* a1_ = (lane < 32) ? slow_gate  : mix_fast;                \
        pS0 = a0_[(size_t)tl_*BH + p];                                         \
        pS1 = a1_[(size_t)tl_*BH + p];                                         \
        if (lane < 32) pS2 = mix_slow[(size_t)tl_*BH + p];                     \
    } } while (0)

    LOADCHUNK(0);
    __syncthreads();

    for (int c = 0; c < NC; ++c) {
        // ---- A: wave 0 computes cumulative decays (slow in lanes<32, fast hi) ----
        if (wid == 0) {
            float aval = (lane < 32) ? __builtin_fmaf(pS1, pS0, 1.0f - pS1) : pS0;
            float b = aval;
#pragma unroll
            for (int d = 1; d < 32; d <<= 1) {
                float y = __shfl_up(b, d, 32);
                if (l31 >= d) b *= y;
            }
            float ib = 1.0f / b;
            if (lane < 32) { scl[0][l31]=b; scl[1][l31]=ib; scl[2][l31]=pS2*b; scl[3][l31]=pS1; }
            else           { scl[4][l31]=b; scl[5][l31]=ib; scl[6][l31]=pS1*b; }
        }
        __syncthreads();   // B0

        // ---- B: all threads convert + stage LDS ----
        {
            const float ib  = scl[1][s_], qsc = scl[2][s_];
            const float g_  = scl[3][s_], ibf = scl[5][s_], qfc = scl[6][s_];
            const float bls = scl[0][LCH-1], blf = scl[4][LCH-1];
            float kv[8] = {pKs0.x,pKs0.y,pKs0.z,pKs0.w,pKs1.x,pKs1.y,pKs1.z,pKs1.w};
            float qv[8] = {pQs0.x,pQs0.y,pQs0.z,pQs0.w,pQs1.x,pQs1.y,pQs1.z,pQs1.w};
            unsigned short kb[8], qb[8];
#pragma unroll
            for (int e = 0; e < 8; ++e) { kb[e] = f2b(kv[e]*ib); qb[e] = f2b(qv[e]*qsc); }
            uint4 kw, qw;
            kw.x = kb[0] | ((unsigned)kb[1]<<16); kw.y = kb[2] | ((unsigned)kb[3]<<16);
            kw.z = kb[4] | ((unsigned)kb[5]<<16); kw.w = kb[6] | ((unsigned)kb[7]<<16);
            qw.x = qb[0] | ((unsigned)qb[1]<<16); qw.y = qb[2] | ((unsigned)qb[3]<<16);
            qw.z = qb[4] | ((unsigned)qb[5]<<16); qw.w = qb[6] | ((unsigned)qb[7]<<16);
            *(uint4*)&Ksl[s_][k0_] = kw;
            *(uint4*)&Qs [s_][k0_] = qw;
#pragma unroll
            for (int e = 0; e < 8; ++e) KTs[k0_+e][s_] = kb[e];

            float vt0 = g_*pVs.x, vt1 = g_*pVs.y;
            VTs[j0_  ][s_] = f2b(vt0);      VTs[j0_+1][s_] = f2b(vt1);
            WTs[j0_  ][s_] = f2b(bls*vt0);  WTs[j0_+1][s_] = f2b(bls*vt1);
            VTf[j0_  ][s_] = f2b(pVf.x);    VTf[j0_+1][s_] = f2b(pVf.y);
            WTf[j0_  ][s_] = f2b(blf*pVf.x); WTf[j0_+1][s_] = f2b(blf*pVf.y);
            unsigned short kf0 = f2b(pKf.x*ibf), kf1 = f2b(pKf.y*ibf);
            Kfl[s_][j0_] = kf0; Kfl[s_][j0_+1] = kf1;
            KTf[j0_][s_] = kf0; KTf[j0_+1][s_] = kf1;
            Qfl[s_][j0_]   = f2b(pQf.x*qfc);
            Qfl[s_][j0_+1] = f2b(pQf.y*qfc);
        }
        __syncthreads();   // B1

        LOADCHUNK(c+1);    // prefetch next chunk (regs), hidden under C1/C2/A

        f32x16 oacc;
#pragma unroll
        for (int r = 0; r < 16; ++r) oacc[r] = 0.0f;
        const int kb16 = 8*hi;

        // ---- C1 ----
        if (wid < 4) {                       // slow-state update: S = bL*S + K~^T V^
            const float bls = scl[0][LCH-1];
#pragma unroll
            for (int r = 0; r < 16; ++r) Sst[r] *= bls;
            const unsigned short* ar = &KTs[32*wid + l31][0];
            const unsigned short* br = &WTs[l31][0];
            Sst = MFMA32(ld8(ar + kb16), ld8(br + kb16), Sst);
            Sst = MFMA32(ld8(ar + kb16 + 16), ld8(br + kb16 + 16), Sst);
        } else if (wid == 4) {               // fast-state update
            const float blf = scl[4][LCH-1];
#pragma unroll
            for (int r = 0; r < 16; ++r) Sst[r] *= blf;
            const unsigned short* ar = &KTf[l31][0];
            const unsigned short* br = &WTf[l31][0];
            Sst = MFMA32(ld8(ar + kb16), ld8(br + kb16), Sst);
            Sst = MFMA32(ld8(ar + kb16 + 16), ld8(br + kb16 + 16), Sst);
        } else if (wid == 5) {               // P_slow
            f32x16 pa;
#pragma unroll
            for (int r = 0; r < 16; ++r) pa[r] = 0.0f;
            const unsigned short* ar = &Qs [l31][0];
            const unsigned short* br = &Ksl[l31][0];
#pragma unroll
            for (int st = 0; st < 8; ++st)
                pa = MFMA32(ld8(ar + kb16 + 16*st), ld8(br + kb16 + 16*st), pa);
#pragma unroll
            for (int r = 0; r < 16; ++r) {
                int tr = CROW(r,hi);
                Psl[tr][l31] = f2b(tr >= l31 ? pa[r] : 0.0f);
            }
        } else if (wid == 6) {               // P_fast
            f32x16 pa;
#pragma unroll
            for (int r = 0; r < 16; ++r) pa[r] = 0.0f;
            const unsigned short* ar = &Qfl[l31][0];
            const unsigned short* br = &Kfl[l31][0];
            pa = MFMA32(ld8(ar + kb16), ld8(br + kb16), pa);
            pa = MFMA32(ld8(ar + kb16 + 16), ld8(br + kb16 + 16), pa);
#pragma unroll
            for (int r = 0; r < 16; ++r) {
                int tr = CROW(r,hi);
                Pfl[tr][l31] = f2b(tr >= l31 ? pa[r] : 0.0f);
            }
        } else {                             // w7: inter-chunk out (reads OLD S bf16)
            const unsigned short* ar = &Qs [l31][0];
            const unsigned short* br = &Sbs[l31][0];
#pragma unroll
            for (int st = 0; st < 8; ++st)
                oacc = MFMA32(ld8(ar + kb16 + 16*st), ld8(br + kb16 + 16*st), oacc);
            const unsigned short* af = &Qfl [l31][0];
            const unsigned short* bf = &Sbfl[l31][0];
            oacc = MFMA32(ld8(af + kb16), ld8(bf + kb16), oacc);
            oacc = MFMA32(ld8(af + kb16 + 16), ld8(bf + kb16 + 16), oacc);
        }
        __syncthreads();   // B2

        // ---- C2 ----
        if (wid < 4) {                       // publish new slow state (bf16)
#pragma unroll
            for (int r = 0; r < 16; ++r) Sbs[l31][32*wid + CROW(r,hi)] = f2b(Sst[r]);
        } else if (wid == 4) {
#pragma unroll
            for (int r = 0; r < 16; ++r) Sbfl[l31][CROW(r,hi)] = f2b(Sst[r]);
        } else if (wid == 7) {               // intra-chunk out + store
            const unsigned short* ar = &Psl[l31][0];
            const unsigned short* br = &VTs[l31][0];
            oacc = MFMA32(ld8(ar + kb16), ld8(br + kb16), oacc);
            oacc = MFMA32(ld8(ar + kb16 + 16), ld8(br + kb16 + 16), oacc);
            const unsigned short* af = &Pfl[l31][0];
            const unsigned short* bf = &VTf[l31][0];
            oacc = MFMA32(ld8(af + kb16), ld8(bf + kb16), oacc);
            oacc = MFMA32(ld8(af + kb16 + 16), ld8(bf + kb16 + 16), oacc);
#pragma unroll
            for (int r = 0; r < 16; ++r) {
                int tr = CROW(r,hi);
                out_y[((size_t)(c*LCH + tr)*BH + p)*VF_ + v0 + l31] = oacc[r];
            }
        }
        // no barrier needed here: B0/B1 of next iteration order Sbs/Ps/VT reuse
    }

    // ---- final states (f32) ----
    if (wid < 4) {
#pragma unroll
        for (int r = 0; r < 16; ++r) {
            int kr = 32*wid + CROW(r,hi);
            dout[BH*KF_*VF_ + ((size_t)p*KS_ + kr)*VS_ + v0 + l31] = Sst[r];
        }
    } else if (wid == 4) {
#pragma unroll
        for (int r = 0; r < 16; ++r) {
            int kr = CROW(r,hi);
            dout[((size_t)p*KF_ + kr)*VF_ + v0 + l31] = Sst[r];
        }
    }
#undef LOADCHUNK
}

extern "C" void kernel_launch(void* const* d_in, const int* in_sizes, int n_in,
                              void* d_out, int out_size, void* d_ws, size_t ws_size,
                              hipStream_t stream)
{
    const float* k_fast     = (const float*)d_in[0];
    const float* v_fast     = (const float*)d_in[1];
    const float* q_fast     = (const float*)d_in[2];
    const float* decay_fast = (const float*)d_in[3];
    const float* k_slow     = (const float*)d_in[4];
    const float* v_slow     = (const float*)d_in[5];
    const float* q_slow     = (const float*)d_in[6];
    const float* decay_slow = (const float*)d_in[7];
    const float* slow_gate  = (const float*)d_in[8];
    const float* mix_fast   = (const float*)d_in[9];
    const float* mix_slow   = (const float*)d_in[10];
    const float* S_fast0    = (const float*)d_in[11];
    const float* S_slow0    = (const float*)d_in[12];
    float* dout = (float*)d_out;

    e90_mfma<<<dim3(256), dim3(NTHR), 0, stream>>>(
        k_fast, v_fast, q_fast, decay_fast,
        k_slow, v_slow, q_slow, decay_slow,
        slow_gate, mix_fast, mix_slow, S_fast0, S_slow0, dout);
}

// Round 3
// 205.379 us; speedup vs baseline: 2.6891x; 1.0487x over previous
//
#include <hip/hip_runtime.h>

#define T_STEPS 2048
#define BH      128
#define KS_     128
#define VS_     64
#define KF_     32
#define VF_     64
#define LCH     32
#define NC      (T_STEPS / LCH)
#define NTHR    512

typedef __attribute__((ext_vector_type(8))) short short8;
typedef __attribute__((ext_vector_type(16))) float f32x16;

#define MFMA32(a,b,c) __builtin_amdgcn_mfma_f32_32x32x16_bf16((a),(b),(c),0,0,0)
#define CROW(r,hi) (((r)&3) + 8*((r)>>2) + 4*(hi))

__device__ __forceinline__ unsigned short f2b(float x) {
    union { float f; unsigned u; } v; v.f = x;
    unsigned r = v.u + 0x7FFFu + ((v.u >> 16) & 1u);
    return (unsigned short)(r >> 16);
}

__device__ __forceinline__ short8 ld8(const unsigned short* p) {
    return *(const short8*)p;
}

__global__ __launch_bounds__(NTHR, 2)
void e90_mfma(const float* __restrict__ k_fast,  const float* __restrict__ v_fast,
              const float* __restrict__ q_fast,  const float* __restrict__ decay_fast,
              const float* __restrict__ k_slow,  const float* __restrict__ v_slow,
              const float* __restrict__ q_slow,  const float* __restrict__ decay_slow,
              const float* __restrict__ slow_gate, const float* __restrict__ mix_fast,
              const float* __restrict__ mix_slow, const float* __restrict__ S_fast0,
              const float* __restrict__ S_slow0, float* __restrict__ dout)
{
    // Natural layouts only (no [k][s] transpose arrays). 136/40-ushort strides
    // give structurally conflict-free b128 reads (8 lanes/bank-group).
    __shared__ __align__(16) unsigned short Qs [LCH][136];   // ms*b_t*q_slow [t][k]
    __shared__ __align__(16) unsigned short Ksl[LCH][136];   // k_slow/b_s    [s][k]
    __shared__ __align__(16) unsigned short Sbs[LCH][136];   // old S_slow^T  [v][k]
    __shared__ __align__(16) unsigned short Psl[LCH][40];    // masked P_slow [t][s]
    __shared__ __align__(16) unsigned short Qfl[LCH][40];    // [t][k]
    __shared__ __align__(16) unsigned short Kfl[LCH][40];    // [s][k]
    __shared__ __align__(16) unsigned short Sbfl[LCH][40];   // old S_fast^T  [v][k]
    __shared__ __align__(16) unsigned short Pfl[LCH][40];    // [t][s]
    __shared__ __align__(16) unsigned short VTs[2][LCH][40]; // (g*v_slow)^T  [v][s]
    __shared__ __align__(16) unsigned short VTf[2][LCH][40]; // v_fast^T      [v][s]

    const int tid  = threadIdx.x;
    const int bid  = blockIdx.x;
    const int xcd  = bid & 7;
    const int jj   = bid >> 3;
    const int p    = xcd * 16 + (jj >> 1);   // (b*H+h) 0..127
    const int v0   = (jj & 1) * 32;          // v-half
    const int lane = tid & 63;
    const int wid  = tid >> 6;
    const int l31  = lane & 31;
    const int hi   = lane >> 5;
    const int s_   = tid >> 4;               // 0..31
    const int j0_  = (tid & 15) * 2;
    const int k0_  = (tid & 15) * 8;

    float* out_y = dout + BH*KF_*VF_ + BH*KS_*VS_;

    // ---- persistent state in C-fragment layout (w0-3 slow, w4 fast) ----
    f32x16 Sst, oacc;
#pragma unroll
    for (int r = 0; r < 16; ++r) { Sst[r] = 0.0f; oacc[r] = 0.0f; }
    if (wid < 4) {
#pragma unroll
        for (int r = 0; r < 16; ++r)
            Sst[r] = S_slow0[((size_t)p*KS_ + 32*wid + CROW(r,hi))*VS_ + v0 + l31];
#pragma unroll
        for (int r = 0; r < 16; ++r) Sbs[l31][32*wid + CROW(r,hi)] = f2b(Sst[r]);
    } else if (wid == 4) {
#pragma unroll
        for (int r = 0; r < 16; ++r)
            Sst[r] = S_fast0[((size_t)p*KF_ + CROW(r,hi))*VF_ + v0 + l31];
#pragma unroll
        for (int r = 0; r < 16; ++r) Sbfl[l31][CROW(r,hi)] = f2b(Sst[r]);
    }

    // ---- chunk-input prefetch registers ----
    float4 pKs0, pKs1, pQs0, pQs1;
    float2 pVs, pVf, pKf, pQf;
    float pL0 = 0.f, pL1 = 0.f, pL2 = 0.f;   // lane-scan inputs

#define LOADCHUNK(CIDX) do {                                                   \
    int tc_ = (CIDX); if (tc_ > NC-1) tc_ = NC-1;                              \
    const int tb_ = tc_ * LCH;                                                 \
    const float* bk_ = k_slow + ((size_t)(tb_+s_)*BH + p)*KS_ + k0_;           \
    pKs0 = *(const float4*)bk_;  pKs1 = *(const float4*)(bk_+4);               \
    const float* bq_ = q_slow + ((size_t)(tb_+s_)*BH + p)*KS_ + k0_;           \
    pQs0 = *(const float4*)bq_;  pQs1 = *(const float4*)(bq_+4);               \
    pVs = *(const float2*)(v_slow + ((size_t)(tb_+s_)*BH + p)*VS_ + v0 + j0_); \
    pVf = *(const float2*)(v_fast + ((size_t)(tb_+s_)*BH + p)*VF_ + v0 + j0_); \
    pKf = *(const float2*)(k_fast + ((size_t)(tb_+s_)*BH + p)*KF_ + j0_);      \
    pQf = *(const float2*)(q_fast + ((size_t)(tb_+s_)*BH + p)*KF_ + j0_);      \
    const size_t so_ = (size_t)(tb_ + l31)*BH + p;                             \
    pL0 = (hi ? decay_fast : decay_slow)[so_];                                 \
    pL1 = (hi ? mix_fast   : slow_gate )[so_];                                 \
    pL2 = hi ? 0.0f : mix_slow[so_];                                           \
    } while (0)

    LOADCHUNK(0);

    float bls = 1.f, blf = 1.f, ib = 1.f, ibf = 1.f, qsc = 0.f, qfc = 0.f, g_s = 0.f;

    for (int c = 0; c < NC; ++c) {
        const int cb = c & 1;
        // ================= R1 =================
        if (c > 0) {
            if (wid < 4) {
#pragma unroll
                for (int r = 0; r < 16; ++r) Sbs[l31][32*wid + CROW(r,hi)] = f2b(Sst[r]);
            } else if (wid == 4) {
#pragma unroll
                for (int r = 0; r < 16; ++r) Sbfl[l31][CROW(r,hi)] = f2b(Sst[r]);
            } else if (wid == 7) {           // intra-out of chunk c-1 + store
                const int pb = cb ^ 1;
                f32x16 o2;
#pragma unroll
                for (int r = 0; r < 16; ++r) o2[r] = 0.0f;
                const unsigned short* ar = &Psl[l31][0];
                const unsigned short* br = &VTs[pb][l31][0];
                oacc = MFMA32(ld8(ar + 8*hi),      ld8(br + 8*hi),      oacc);
                oacc = MFMA32(ld8(ar + 16 + 8*hi), ld8(br + 16 + 8*hi), oacc);
                const unsigned short* af = &Pfl[l31][0];
                const unsigned short* bf = &VTf[pb][l31][0];
                o2 = MFMA32(ld8(af + 8*hi),      ld8(bf + 8*hi),      o2);
                o2 = MFMA32(ld8(af + 16 + 8*hi), ld8(bf + 16 + 8*hi), o2);
#pragma unroll
                for (int r = 0; r < 16; ++r) {
                    int tr = CROW(r,hi);
                    out_y[((size_t)((c-1)*LCH + tr)*BH + p)*VF_ + v0 + l31] = oacc[r] + o2[r];
                }
            }
        }
        // ---- in-wave decay scan (every wave; lanes<32 slow, hi fast) ----
        {
            float a = hi ? pL0 : __builtin_fmaf(pL1, pL0, 1.0f - pL1);
            float b = a;
#pragma unroll
            for (int d = 1; d < 32; d <<= 1) {
                float y = __shfl_up(b, d, 32);
                if (l31 >= d) b *= y;
            }
            float bs_s = __shfl(b, s_);
            float bf_s = __shfl(b, 32 + s_);
            bls = __shfl(b, 31);
            blf = __shfl(b, 63);
            g_s = __shfl(pL1, s_);
            float mf_s = __shfl(pL1, 32 + s_);
            float ms_s = __shfl(pL2, s_);
            ib  = 1.0f / bs_s;
            ibf = 1.0f / bf_s;
            qsc = ms_s * bs_s;
            qfc = mf_s * bf_s;
        }
        // ---- stage chunk c into LDS ----
        {
            float kv[8] = {pKs0.x,pKs0.y,pKs0.z,pKs0.w,pKs1.x,pKs1.y,pKs1.z,pKs1.w};
            float qv[8] = {pQs0.x,pQs0.y,pQs0.z,pQs0.w,pQs1.x,pQs1.y,pQs1.z,pQs1.w};
            unsigned short kb[8], qb[8];
#pragma unroll
            for (int e = 0; e < 8; ++e) { kb[e] = f2b(kv[e]*ib); qb[e] = f2b(qv[e]*qsc); }
            uint4 kw, qw;
            kw.x = kb[0] | ((unsigned)kb[1]<<16); kw.y = kb[2] | ((unsigned)kb[3]<<16);
            kw.z = kb[4] | ((unsigned)kb[5]<<16); kw.w = kb[6] | ((unsigned)kb[7]<<16);
            qw.x = qb[0] | ((unsigned)qb[1]<<16); qw.y = qb[2] | ((unsigned)qb[3]<<16);
            qw.z = qb[4] | ((unsigned)qb[5]<<16); qw.w = qb[6] | ((unsigned)qb[7]<<16);
            *(uint4*)&Ksl[s_][k0_] = kw;
            *(uint4*)&Qs [s_][k0_] = qw;

            float vt0 = g_s*pVs.x, vt1 = g_s*pVs.y;
            VTs[cb][j0_  ][s_] = f2b(vt0);
            VTs[cb][j0_+1][s_] = f2b(vt1);
            VTf[cb][j0_  ][s_] = f2b(pVf.x);
            VTf[cb][j0_+1][s_] = f2b(pVf.y);
            unsigned kfp = f2b(pKf.x*ibf) | ((unsigned)f2b(pKf.y*ibf) << 16);
            *(unsigned*)&Kfl[s_][j0_] = kfp;
            unsigned qfp = f2b(pQf.x*qfc) | ((unsigned)f2b(pQf.y*qfc) << 16);
            *(unsigned*)&Qfl[s_][j0_] = qfp;
        }
        __syncthreads();   // barrier A

        // ================= R2 =================
        LOADCHUNK(c + 1);  // prefetch next chunk; consumed after barrier B

        if (wid < 4) {                       // slow state: S = bL*(S + K~^T Vg)
            short8 a1, a2;
#pragma unroll
            for (int e = 0; e < 8; ++e) {
                a1[e] = (short)Ksl[8*hi + e][32*wid + l31];
                a2[e] = (short)Ksl[16 + 8*hi + e][32*wid + l31];
            }
            const unsigned short* br = &VTs[cb][l31][0];
            Sst = MFMA32(a1, ld8(br + 8*hi),      Sst);
            Sst = MFMA32(a2, ld8(br + 16 + 8*hi), Sst);
#pragma unroll
            for (int r = 0; r < 16; ++r) Sst[r] *= bls;
        } else if (wid == 4) {               // fast state
            short8 a1, a2;
#pragma unroll
            for (int e = 0; e < 8; ++e) {
                a1[e] = (short)Kfl[8*hi + e][l31];
                a2[e] = (short)Kfl[16 + 8*hi + e][l31];
            }
            const unsigned short* br = &VTf[cb][l31][0];
            Sst = MFMA32(a1, ld8(br + 8*hi),      Sst);
            Sst = MFMA32(a2, ld8(br + 16 + 8*hi), Sst);
#pragma unroll
            for (int r = 0; r < 16; ++r) Sst[r] *= blf;
        } else if (wid == 5) {               // P_slow (dual chains)
            f32x16 p1, p2;
#pragma unroll
            for (int r = 0; r < 16; ++r) { p1[r] = 0.0f; p2[r] = 0.0f; }
            const unsigned short* ar = &Qs [l31][0];
            const unsigned short* br = &Ksl[l31][0];
            const int kb = 8*hi;
#pragma unroll
            for (int st = 0; st < 8; st += 2) {
                p1 = MFMA32(ld8(ar + kb + 16*st),     ld8(br + kb + 16*st),     p1);
                p2 = MFMA32(ld8(ar + kb + 16*(st+1)), ld8(br + kb + 16*(st+1)), p2);
            }
#pragma unroll
            for (int r = 0; r < 16; ++r) {
                int tr = CROW(r,hi);
                Psl[tr][l31] = f2b(tr >= l31 ? p1[r] + p2[r] : 0.0f);
            }
        } else if (wid == 6) {               // P_fast
            f32x16 p1;
#pragma unroll
            for (int r = 0; r < 16; ++r) p1[r] = 0.0f;
            const unsigned short* ar = &Qfl[l31][0];
            const unsigned short* br = &Kfl[l31][0];
            p1 = MFMA32(ld8(ar + 8*hi),      ld8(br + 8*hi),      p1);
            p1 = MFMA32(ld8(ar + 16 + 8*hi), ld8(br + 16 + 8*hi), p1);
#pragma unroll
            for (int r = 0; r < 16; ++r) {
                int tr = CROW(r,hi);
                Pfl[tr][l31] = f2b(tr >= l31 ? p1[r] : 0.0f);
            }
        } else {                             // w7: inter-chunk out (dual chains)
            f32x16 o1, o2;
#pragma unroll
            for (int r = 0; r < 16; ++r) { o1[r] = 0.0f; o2[r] = 0.0f; }
            const unsigned short* ar = &Qs [l31][0];
            const unsigned short* br = &Sbs[l31][0];
            const int kb = 8*hi;
#pragma unroll
            for (int st = 0; st < 8; st += 2) {
                o1 = MFMA32(ld8(ar + kb + 16*st),     ld8(br + kb + 16*st),     o1);
                o2 = MFMA32(ld8(ar + kb + 16*(st+1)), ld8(br + kb + 16*(st+1)), o2);
            }
            const unsigned short* af = &Qfl [l31][0];
            const unsigned short* bf = &Sbfl[l31][0];
            o1 = MFMA32(ld8(af + 8*hi),      ld8(bf + 8*hi),      o1);
            o2 = MFMA32(ld8(af + 16 + 8*hi), ld8(bf + 16 + 8*hi), o2);
#pragma unroll
            for (int r = 0; r < 16; ++r) oacc[r] = o1[r] + o2[r];
        }
        __syncthreads();   // barrier B
    }

    // ---- epilogue: intra-out + store for chunk NC-1 ----
    if (wid == 7) {
        const int pb = (NC - 1) & 1;
        f32x16 o2;
#pragma unroll
        for (int r = 0; r < 16; ++r) o2[r] = 0.0f;
        const unsigned short* ar = &Psl[l31][0];
        const unsigned short* br = &VTs[pb][l31][0];
        oacc = MFMA32(ld8(ar + 8*hi),      ld8(br + 8*hi),      oacc);
        oacc = MFMA32(ld8(ar + 16 + 8*hi), ld8(br + 16 + 8*hi), oacc);
        const unsigned short* af = &Pfl[l31][0];
        const unsigned short* bf = &VTf[pb][l31][0];
        o2 = MFMA32(ld8(af + 8*hi),      ld8(bf + 8*hi),      o2);
        o2 = MFMA32(ld8(af + 16 + 8*hi), ld8(bf + 16 + 8*hi), o2);
#pragma unroll
        for (int r = 0; r < 16; ++r) {
            int tr = CROW(r,hi);
            out_y[((size_t)((NC-1)*LCH + tr)*BH + p)*VF_ + v0 + l31] = oacc[r] + o2[r];
        }
    }

    // ---- final states (f32) ----
    if (wid < 4) {
#pragma unroll
        for (int r = 0; r < 16; ++r)
            dout[BH*KF_*VF_ + ((size_t)p*KS_ + 32*wid + CROW(r,hi))*VS_ + v0 + l31] = Sst[r];
    } else if (wid == 4) {
#pragma unroll
        for (int r = 0; r < 16; ++r)
            dout[((size_t)p*KF_ + CROW(r,hi))*VF_ + v0 + l31] = Sst[r];
    }
#undef LOADCHUNK
}

extern "C" void kernel_launch(void* const* d_in, const int* in_sizes, int n_in,
                              void* d_out, int out_size, void* d_ws, size_t ws_size,
                              hipStream_t stream)
{
    const float* k_fast     = (const float*)d_in[0];
    const float* v_fast     = (const float*)d_in[1];
    const float* q_fast     = (const float*)d_in[2];
    const float* decay_fast = (const float*)d_in[3];
    const float* k_slow     = (const float*)d_in[4];
    const float* v_slow     = (const float*)d_in[5];
    const float* q_slow     = (const float*)d_in[6];
    const float* decay_slow = (const float*)d_in[7];
    const float* slow_gate  = (const float*)d_in[8];
    const float* mix_fast   = (const float*)d_in[9];
    const float* mix_slow   = (const float*)d_in[10];
    const float* S_fast0    = (const float*)d_in[11];
    const float* S_slow0    = (const float*)d_in[12];
    float* dout = (float*)d_out;

    e90_mfma<<<dim3(256), dim3(NTHR), 0, stream>>>(
        k_fast, v_fast, q_fast, decay_fast,
        k_slow, v_slow, q_slow, decay_slow,
        slow_gate, mix_fast, mix_slow, S_fast0, S_slow0, dout);
}

// Round 6
// 186.744 us; speedup vs baseline: 2.9574x; 1.0998x over previous
//
#include <hip/hip_runtime.h>

#define T_STEPS 2048
#define BH      128
#define KS_     128
#define VS_     64
#define KF_     32
#define VF_     64
#define LCH     32
#define NC      (T_STEPS / LCH)
#define NTHR    512

typedef __attribute__((ext_vector_type(8))) short short8;
typedef __attribute__((ext_vector_type(16))) float f32x16;

#define MFMA32(a,b,c) __builtin_amdgcn_mfma_f32_32x32x16_bf16((a),(b),(c),0,0,0)
#define CROW(r,hi) (((r)&3) + 8*((r)>>2) + 4*(hi))

__device__ __forceinline__ unsigned short f2b(float x) {
    union { float f; unsigned u; } v; v.f = x;
    unsigned r = v.u + 0x7FFFu + ((v.u >> 16) & 1u);
    return (unsigned short)(r >> 16);
}
__device__ __forceinline__ unsigned cvtpk(float lo, float hi_) {
    unsigned r;
    asm("v_cvt_pk_bf16_f32 %0, %1, %2" : "=v"(r) : "v"(lo), "v"(hi_));
    return r;
}
__device__ __forceinline__ short8 ld8(const unsigned short* p) {
    return *(const short8*)p;
}

// Single-kernel full-T scan (R3-validated math), restructured to ONE barrier
// per chunk: dbuf on all chunk arrays ([2]), VT 3-buffered, y-store moved
// into the MFMA phase, decay-scan hoisted one chunk early (depth-2 scalar
// prefetch). 91KB LDS, 1 block/CU, 256 blocks.
__global__ __launch_bounds__(NTHR, 2)
void e90_mfma(const float* __restrict__ k_fast,  const float* __restrict__ v_fast,
              const float* __restrict__ q_fast,  const float* __restrict__ decay_fast,
              const float* __restrict__ k_slow,  const float* __restrict__ v_slow,
              const float* __restrict__ q_slow,  const float* __restrict__ decay_slow,
              const float* __restrict__ slow_gate, const float* __restrict__ mix_fast,
              const float* __restrict__ mix_slow, const float* __restrict__ S_fast0,
              const float* __restrict__ S_slow0, float* __restrict__ dout)
{
    __shared__ __align__(16) unsigned short Qs  [2][LCH][136];
    __shared__ __align__(16) unsigned short Ksl [2][LCH][136];
    __shared__ __align__(16) unsigned short Sbs [2][LCH][136];
    __shared__ __align__(16) unsigned short Psl [2][LCH][40];
    __shared__ __align__(16) unsigned short Pfl [2][LCH][40];
    __shared__ __align__(16) unsigned short Qfl [2][LCH][40];
    __shared__ __align__(16) unsigned short Kfl [2][LCH][40];
    __shared__ __align__(16) unsigned short Sbfl[2][LCH][40];
    __shared__ __align__(16) unsigned short VTs [3][LCH][40];
    __shared__ __align__(16) unsigned short VTf [3][LCH][40];

    const int tid  = threadIdx.x;
    const int bid  = blockIdx.x;
    const int xcd  = bid & 7;
    const int jj   = bid >> 3;
    const int p    = xcd * 16 + (jj >> 1);   // (b*H+h) 0..127
    const int v0   = (jj & 1) * 32;          // v-half
    const int lane = tid & 63;
    const int wid  = tid >> 6;
    const int l31  = lane & 31;
    const int hi   = lane >> 5;
    const int s_   = tid >> 4;               // 0..31
    const int j0_  = (tid & 15) * 2;
    const int k0_  = (tid & 15) * 8;

    float* out_y = dout + BH*KF_*VF_ + BH*KS_*VS_;

    // ---- state init (R3-identical) + initial publish into buffer 0 ----
    f32x16 Sst, oacc;
#pragma unroll
    for (int r = 0; r < 16; ++r) { Sst[r] = 0.0f; oacc[r] = 0.0f; }
    if (wid < 4) {
#pragma unroll
        for (int r = 0; r < 16; ++r)
            Sst[r] = S_slow0[((size_t)p*KS_ + 32*wid + CROW(r,hi))*VS_ + v0 + l31];
#pragma unroll
        for (int r = 0; r < 16; ++r) Sbs[0][l31][32*wid + CROW(r,hi)] = f2b(Sst[r]);
    } else if (wid == 4) {
#pragma unroll
        for (int r = 0; r < 16; ++r)
            Sst[r] = S_fast0[((size_t)p*KF_ + CROW(r,hi))*VF_ + v0 + l31];
#pragma unroll
        for (int r = 0; r < 16; ++r) Sbfl[0][l31][CROW(r,hi)] = f2b(Sst[r]);
    }

    // ---- prefetch regs ----
    float4 pKs0, pKs1, pQs0, pQs1;
    float2 pVs, pVf, pKf, pQf;
    float pL0 = 0.f, pL1 = 0.f, pL2 = 0.f;
    float bls = 1.f, blf = 1.f, ib = 1.f, ibf = 1.f, qsc = 0.f, qfc = 0.f, g_s = 0.f;

#define LOADVEC(CIDX) do {                                                     \
    int tc_ = (CIDX); if (tc_ > NC-1) tc_ = NC-1;                              \
    const int tb_ = tc_ * LCH;                                                 \
    const float* bk_ = k_slow + ((size_t)(tb_+s_)*BH + p)*KS_ + k0_;           \
    pKs0 = *(const float4*)bk_;  pKs1 = *(const float4*)(bk_+4);               \
    const float* bq_ = q_slow + ((size_t)(tb_+s_)*BH + p)*KS_ + k0_;           \
    pQs0 = *(const float4*)bq_;  pQs1 = *(const float4*)(bq_+4);               \
    pVs = *(const float2*)(v_slow + ((size_t)(tb_+s_)*BH + p)*VS_ + v0 + j0_); \
    pVf = *(const float2*)(v_fast + ((size_t)(tb_+s_)*BH + p)*VF_ + v0 + j0_); \
    pKf = *(const float2*)(k_fast + ((size_t)(tb_+s_)*BH + p)*KF_ + j0_);      \
    pQf = *(const float2*)(q_fast + ((size_t)(tb_+s_)*BH + p)*KF_ + j0_);      \
    } while (0)

#define LOADSCL(CIDX) do {                                                     \
    int tc_ = (CIDX); if (tc_ > NC-1) tc_ = NC-1;                              \
    const size_t so_ = (size_t)(tc_*LCH + l31)*BH + p;                         \
    pL0 = (hi ? decay_fast : decay_slow)[so_];                                 \
    pL1 = (hi ? mix_fast   : slow_gate )[so_];                                 \
    pL2 = hi ? 0.0f : mix_slow[so_];                                           \
    } while (0)

    // scan consumes pL* and produces the per-chunk scale set (R3-identical math)
#define SCAN() do {                                                            \
    float a_ = hi ? pL0 : __builtin_fmaf(pL1, pL0, 1.0f - pL1);                \
    float b_ = a_;                                                             \
    _Pragma("unroll")                                                          \
    for (int d = 1; d < 32; d <<= 1) {                                         \
        float y_ = __shfl_up(b_, d, 32);                                       \
        if (l31 >= d) b_ *= y_;                                                \
    }                                                                          \
    float bs_s = __shfl(b_, s_);                                               \
    float bf_s = __shfl(b_, 32 + s_);                                          \
    bls = __shfl(b_, 31);                                                      \
    blf = __shfl(b_, 63);                                                      \
    g_s = __shfl(pL1, s_);                                                     \
    float mf_s = __shfl(pL1, 32 + s_);                                         \
    float ms_s = __shfl(pL2, s_);                                              \
    ib  = 1.0f / bs_s;                                                         \
    ibf = 1.0f / bf_s;                                                         \
    qsc = ms_s * bs_s;                                                         \
    qfc = mf_s * bf_s;                                                         \
    } while (0)

#define STAGE(J2, J3) do {                                                     \
    uint4 kw, qw;                                                              \
    kw.x = cvtpk(pKs0.x*ib, pKs0.y*ib);  kw.y = cvtpk(pKs0.z*ib, pKs0.w*ib);   \
    kw.z = cvtpk(pKs1.x*ib, pKs1.y*ib);  kw.w = cvtpk(pKs1.z*ib, pKs1.w*ib);   \
    qw.x = cvtpk(pQs0.x*qsc, pQs0.y*qsc); qw.y = cvtpk(pQs0.z*qsc, pQs0.w*qsc);\
    qw.z = cvtpk(pQs1.x*qsc, pQs1.y*qsc); qw.w = cvtpk(pQs1.z*qsc, pQs1.w*qsc);\
    *(uint4*)&Ksl[J2][s_][k0_] = kw;                                           \
    *(uint4*)&Qs [J2][s_][k0_] = qw;                                           \
    float vt0 = g_s*pVs.x, vt1 = g_s*pVs.y;                                    \
    VTs[J3][j0_  ][s_] = f2b(vt0);                                             \
    VTs[J3][j0_+1][s_] = f2b(vt1);                                             \
    VTf[J3][j0_  ][s_] = f2b(pVf.x);                                           \
    VTf[J3][j0_+1][s_] = f2b(pVf.y);                                           \
    unsigned kfp = cvtpk(pKf.x*ibf, pKf.y*ibf);                                \
    *(unsigned*)&Kfl[J2][s_][j0_] = kfp;                                       \
    unsigned qfp = cvtpk(pQf.x*qfc, pQf.y*qfc);                                \
    *(unsigned*)&Qfl[J2][s_][j0_] = qfp;                                       \
    } while (0)

    // y-store for chunk CP (reads Psl/Pfl[CP&1], VTs/VTf[CP%3], oacc)
#define YSTORE(CP) do {                                                        \
    const int p2_ = (CP) & 1, p3_ = (CP) % 3;                                  \
    f32x16 o2;                                                                 \
    _Pragma("unroll")                                                          \
    for (int r = 0; r < 16; ++r) o2[r] = 0.0f;                                 \
    const unsigned short* ar = &Psl[p2_][l31][0];                              \
    const unsigned short* br = &VTs[p3_][l31][0];                              \
    oacc = MFMA32(ld8(ar + 8*hi),      ld8(br + 8*hi),      oacc);             \
    oacc = MFMA32(ld8(ar + 16 + 8*hi), ld8(br + 16 + 8*hi), oacc);             \
    const unsigned short* af = &Pfl[p2_][l31][0];                              \
    const unsigned short* bf = &VTf[p3_][l31][0];                              \
    o2 = MFMA32(ld8(af + 8*hi),      ld8(bf + 8*hi),      o2);                 \
    o2 = MFMA32(ld8(af + 16 + 8*hi), ld8(bf + 16 + 8*hi), o2);                 \
    _Pragma("unroll")                                                          \
    for (int r = 0; r < 16; ++r) {                                             \
        int tr = CROW(r,hi);                                                   \
        out_y[((size_t)((CP)*LCH + tr)*BH + p)*VF_ + v0 + l31] = oacc[r] + o2[r]; \
    }                                                                          \
    } while (0)

    // ---- prologue: scan(0), stage(0), one barrier ----
    LOADVEC(0);
    LOADSCL(0);
    SCAN();          // res for chunk 0
    LOADSCL(1);      // consumed by SCAN at end of iter 0 (res for chunk 1)
    STAGE(0, 0);
    __syncthreads();

    for (int c = 0; c < NC; ++c) {
        const int i2 = c & 1;
        const int i3 = c % 3;

        LOADVEC(c + 1);   // consumed at STAGE(c+1) later this iteration

        // ================= MFMA phase (chunk c) =================
        if (wid < 4) {                       // slow state: S = bL*(S + K~^T Vg)
            short8 a1, a2;
#pragma unroll
            for (int e = 0; e < 8; ++e) {
                a1[e] = (short)Ksl[i2][8*hi + e][32*wid + l31];
                a2[e] = (short)Ksl[i2][16 + 8*hi + e][32*wid + l31];
            }
            const unsigned short* br = &VTs[i3][l31][0];
            Sst = MFMA32(a1, ld8(br + 8*hi),      Sst);
            Sst = MFMA32(a2, ld8(br + 16 + 8*hi), Sst);
#pragma unroll
            for (int r = 0; r < 16; ++r) Sst[r] *= bls;
        } else if (wid == 4) {               // fast state
            short8 a1, a2;
#pragma unroll
            for (int e = 0; e < 8; ++e) {
                a1[e] = (short)Kfl[i2][8*hi + e][l31];
                a2[e] = (short)Kfl[i2][16 + 8*hi + e][l31];
            }
            const unsigned short* br = &VTf[i3][l31][0];
            Sst = MFMA32(a1, ld8(br + 8*hi),      Sst);
            Sst = MFMA32(a2, ld8(br + 16 + 8*hi), Sst);
#pragma unroll
            for (int r = 0; r < 16; ++r) Sst[r] *= blf;
        } else if (wid == 5) {               // P_slow (dual chains)
            f32x16 p1, p2;
#pragma unroll
            for (int r = 0; r < 16; ++r) { p1[r] = 0.0f; p2[r] = 0.0f; }
            const unsigned short* ar = &Qs [i2][l31][0];
            const unsigned short* br = &Ksl[i2][l31][0];
            const int kb = 8*hi;
#pragma unroll
            for (int st = 0; st < 8; st += 2) {
                p1 = MFMA32(ld8(ar + kb + 16*st),     ld8(br + kb + 16*st),     p1);
                p2 = MFMA32(ld8(ar + kb + 16*(st+1)), ld8(br + kb + 16*(st+1)), p2);
            }
#pragma unroll
            for (int r = 0; r < 16; ++r) {
                int tr = CROW(r,hi);
                Psl[i2][tr][l31] = f2b(tr >= l31 ? p1[r] + p2[r] : 0.0f);
            }
        } else if (wid == 6) {               // P_fast
            f32x16 p1;
#pragma unroll
            for (int r = 0; r < 16; ++r) p1[r] = 0.0f;
            const unsigned short* ar = &Qfl[i2][l31][0];
            const unsigned short* br = &Kfl[i2][l31][0];
            p1 = MFMA32(ld8(ar + 8*hi),      ld8(br + 8*hi),      p1);
            p1 = MFMA32(ld8(ar + 16 + 8*hi), ld8(br + 16 + 8*hi), p1);
#pragma unroll
            for (int r = 0; r < 16; ++r) {
                int tr = CROW(r,hi);
                Pfl[i2][tr][l31] = f2b(tr >= l31 ? p1[r] : 0.0f);
            }
        } else {                             // wid 7: y-store(c-1), then inter-out(c)
            if (c > 0) YSTORE(c - 1);
            f32x16 o1, o2;
#pragma unroll
            for (int r = 0; r < 16; ++r) { o1[r] = 0.0f; o2[r] = 0.0f; }
            const unsigned short* ar = &Qs [i2][l31][0];
            const unsigned short* br = &Sbs[i2][l31][0];
            const int kb = 8*hi;
#pragma unroll
            for (int st = 0; st < 8; st += 2) {
                o1 = MFMA32(ld8(ar + kb + 16*st),     ld8(br + kb + 16*st),     o1);
                o2 = MFMA32(ld8(ar + kb + 16*(st+1)), ld8(br + kb + 16*(st+1)), o2);
            }
            const unsigned short* af = &Qfl [i2][l31][0];
            const unsigned short* bf = &Sbfl[i2][l31][0];
            o1 = MFMA32(ld8(af + 8*hi),      ld8(bf + 8*hi),      o1);
            o2 = MFMA32(ld8(af + 16 + 8*hi), ld8(bf + 16 + 8*hi), o2);
#pragma unroll
            for (int r = 0; r < 16; ++r) oacc[r] = o1[r] + o2[r];
        }

        // scan for chunk c+1 (pL* loaded one chunk ago); then depth-2 reload
        SCAN();
        LOADSCL(c + 2);

        // ================= stage phase (chunk c+1) =================
        if (c < NC - 1) {
            const int j2 = (c + 1) & 1;
            const int j3 = (c + 1) % 3;
            if (wid < 4) {
#pragma unroll
                for (int r = 0; r < 16; ++r) Sbs[j2][l31][32*wid + CROW(r,hi)] = f2b(Sst[r]);
            } else if (wid == 4) {
#pragma unroll
                for (int r = 0; r < 16; ++r) Sbfl[j2][l31][CROW(r,hi)] = f2b(Sst[r]);
            }
            STAGE(j2, j3);
        }
        __syncthreads();
    }

    // ---- epilogue: y-store for last chunk, final states ----
    if (wid == 7) {
        YSTORE(NC - 1);
    }
    if (wid < 4) {
#pragma unroll
        for (int r = 0; r < 16; ++r)
            dout[BH*KF_*VF_ + ((size_t)p*KS_ + 32*wid + CROW(r,hi))*VS_ + v0 + l31] = Sst[r];
    } else if (wid == 4) {
#pragma unroll
        for (int r = 0; r < 16; ++r)
            dout[((size_t)p*KF_ + CROW(r,hi))*VF_ + v0 + l31] = Sst[r];
    }
#undef LOADVEC
#undef LOADSCL
#undef SCAN
#undef STAGE
#undef YSTORE
}

extern "C" void kernel_launch(void* const* d_in, const int* in_sizes, int n_in,
                              void* d_out, int out_size, void* d_ws, size_t ws_size,
                              hipStream_t stream)
{
    const float* k_fast     = (const float*)d_in[0];
    const float* v_fast     = (const float*)d_in[1];
    const float* q_fast     = (const float*)d_in[2];
    const float* decay_fast = (const float*)d_in[3];
    const float* k_slow     = (const float*)d_in[4];
    const float* v_slow     = (const float*)d_in[5];
    const float* q_slow     = (const float*)d_in[6];
    const float* decay_slow = (const float*)d_in[7];
    const float* slow_gate  = (const float*)d_in[8];
    const float* mix_fast   = (const float*)d_in[9];
    const float* mix_slow   = (const float*)d_in[10];
    const float* S_fast0    = (const float*)d_in[11];
    const float* S_slow0    = (const float*)d_in[12];
    float* dout = (float*)d_out;

    e90_mfma<<<dim3(256), dim3(NTHR), 0, stream>>>(
        k_fast, v_fast, q_fast, decay_fast,
        k_slow, v_slow, q_slow, decay_slow,
        slow_gate, mix_fast, mix_slow, S_fast0, S_slow0, dout);
}